// Round 6
// baseline (205.764 us; speedup 1.0000x reference)
//
#include <hip/hip_runtime.h>
#include <math.h>

#define NROWS 131072
#define XC    17      // FLOW_SIZE+1
#define ROWSB 64      // rows per block
#define HID   256
#define NB    128
#define NCOL  1024
#define LOG2E 1.44269504088896340736f

typedef __attribute__((ext_vector_type(8))) short bf16x8;
typedef __attribute__((ext_vector_type(4))) float f32x4;

#if __has_builtin(__builtin_amdgcn_exp2f)
#define EXP2F(v) __builtin_amdgcn_exp2f(v)
#else
#define EXP2F(v) exp2f(v)
#endif
#if __has_builtin(__builtin_amdgcn_rcpf)
#define RCPF(v) __builtin_amdgcn_rcpf(v)
#else
#define RCPF(v) (1.f / (v))
#endif

__device__ __forceinline__ unsigned short f2bf(float f) {
    unsigned int u = __float_as_uint(f);
    return (unsigned short)((u + 0x7FFFu + ((u >> 16) & 1u)) >> 16);  // RNE
}

// 16-lane reduction on the VALU via DPP (validated; no LDS-pipe traffic).
__device__ __forceinline__ float red16(float v) {
    int x;
    x = __builtin_amdgcn_update_dpp(0, __float_as_int(v), 0xB1, 0xF, 0xF, true);
    v += __int_as_float(x);
    x = __builtin_amdgcn_update_dpp(0, __float_as_int(v), 0x4E, 0xF, 0xF, true);
    v += __int_as_float(x);
    x = __builtin_amdgcn_update_dpp(0, __float_as_int(v), 0x141, 0xF, 0xF, true);
    v += __int_as_float(x);
    x = __builtin_amdgcn_update_dpp(0, __float_as_int(v), 0x140, 0xF, 0xF, true);
    v += __int_as_float(x);
    return v;
}

// R13: coalesced LDS-transpose prep (unchanged).
__global__ void prep_w2(const float* __restrict__ W2, unsigned short* __restrict__ w2t) {
    __shared__ __align__(16) unsigned short tkT[32][80];  // [col][k], stride 160B
    const int tid = threadIdx.x;
    const int k0 = (blockIdx.x & 3) * 64;
    const int c0 = (blockIdx.x >> 2) * 32;
    const int c4 = (tid & 7) * 4;        // 4-col group
    const int kk = (tid >> 3) * 2;       // k-pair
    const float4 r0 = *(const float4*)&W2[(size_t)(k0 + kk) * NCOL + c0 + c4];
    const float4 r1 = *(const float4*)&W2[(size_t)(k0 + kk + 1) * NCOL + c0 + c4];
    const float v0[4] = {r0.x, r0.y, r0.z, r0.w};
    const float v1[4] = {r1.x, r1.y, r1.z, r1.w};
    #pragma unroll
    for (int i = 0; i < 4; ++i) {
        const unsigned int p = (unsigned int)f2bf(v0[i] * LOG2E)
                             | ((unsigned int)f2bf(v1[i] * LOG2E) << 16);
        *(unsigned int*)&tkT[c4 + i][kk] = p;
    }
    __syncthreads();
    const int g = tid & 7, c = tid >> 3;
    const uint4 q = *(const uint4*)&tkT[c][g * 8];
    *(uint4*)&w2t[(size_t)(c0 + c) * HID + k0 + ((g ^ (c & 7)) << 3)] = q;
}

// R19: LDS-pipe roofline fix. All 4 waves previously read IDENTICAL B-frag
// streams (B addr independent of w) -> 2048 ds_read_b128/block ~= 24.6K LDS
// cycles/block; x8 blocks/CU ~= the entire 117us runtime. Re-tile waves to
// 32 rows x 64 cols (rw=w&1, cw=w>>1): B-reads halve (each bf feeds 2 rt
// MFMAs). Row epilogue spans 2 waves; merge is ADDITIVE (local thr clamps
// make num=num_lo+num_hi, T=T_lo+T_hi, eb=eb_lo+eb_hi exact) via a 2KB
// float4-triple LDS buffer + 1 barrier/t. Phase-1 xA reads moved to global
// (wave-uniform rows -> scalar cache), off the LDS pipe.
__global__ __launch_bounds__(256, 3)
void gplc6(const float* __restrict__ x,
           const float* __restrict__ W1,
           const float* __restrict__ b1,
           const unsigned short* __restrict__ w2t,
           const float* __restrict__ b2,
           float* __restrict__ out)
{
    __shared__ float xs[ROWSB * XC];                       // 4352 B
    __shared__ __align__(16) union {
        unsigned short hb[ROWSB * HID];                    // 32 KB (phase 1)
        struct {
            unsigned short w2[2][NB * 64];                 // 32 KB (t-loop dbuf)
            float mrg[2][ROWSB][4];                        // 2 KB merge triples
        } g;
    } u;                                                   // 34816 B; total 39168 B

    const int tid  = threadIdx.x;
    const int lane = tid & 63;
    const int w    = tid >> 6;
    const int rw   = w & 1;           // row half: rows rw*32 .. rw*32+31
    const int cw   = w >> 1;          // col half: cols cw*64 .. cw*64+63
    const int quad = lane >> 4;
    const int l15  = lane & 15;
    const int ksw  = (lane & 7) << 3; // B-frag k swizzle (validated: 0 conflicts)
    const size_t r0 = (size_t)blockIdx.x * ROWSB;

    for (int i = tid; i < ROWSB * XC; i += 256) xs[i] = x[r0 * XC + i];
    const int cp = tid & 127, hlf = tid >> 7;
    float w1r[16];
    #pragma unroll
    for (int i = 0; i < 8; ++i) {
        const float2 t2 = *(const float2*)&W1[i * HID + 2 * cp];
        w1r[2 * i] = t2.x; w1r[2 * i + 1] = t2.y;
    }
    const float2 b1v = *(const float2*)&b1[2 * cp];

    // ---- phase 1: h = relu(xA@W1+b1) -> bf16 LDS, granule-XOR row swizzle.
    // xA read from GLOBAL with wave-uniform row -> scalar path, not LDS pipe.
    for (int r = 0; r < 32; ++r) {
        const int row = __builtin_amdgcn_readfirstlane(hlf * 32 + r);
        const float* xr = x + (r0 + row) * XC;
        float a0 = b1v.x, a1 = b1v.y;
        #pragma unroll
        for (int i = 0; i < 8; ++i) {
            const float xv = xr[i];
            a0 = fmaf(xv, w1r[2 * i], a0);
            a1 = fmaf(xv, w1r[2 * i + 1], a1);
        }
        a0 = fmaxf(a0, 0.f); a1 = fmaxf(a1, 0.f);
        const int eidx = row * HID + (((cp >> 2) ^ (row & 15)) << 3) + ((cp & 3) << 1);
        *(unsigned int*)&u.hb[eidx] = (unsigned int)f2bf(a0) | ((unsigned int)f2bf(a1) << 16);
    }
    __syncthreads();

    // ---- A-fragment register cache: 32 rows x 256 K per wave (64 VGPR).
    bf16x8 afr[2][8];
    #pragma unroll
    for (int rt = 0; rt < 2; ++rt)
        #pragma unroll
        for (int kf = 0; kf < 8; ++kf) {
            const int row = rw * 32 + rt * 16 + l15;    // row&15 == l15
            afr[rt][kf] = *(const bf16x8*)&u.hb[row * HID + (((kf * 4 + quad) ^ l15) << 3)];
        }
    __syncthreads();   // hb dead; union region becomes w2 dbuf + mrg

    auto stage = [&](int n) {
        const int t = n >> 2, kc = n & 3, buf = n & 1;
        #pragma unroll
        for (int j = 0; j < 4; ++j) {
            const int ob = (w * 4 + j) * 512;              // wave-uniform LDS base
            const int c  = (ob >> 6) + (lane >> 3);        // local col 0..127
            const int kl = (lane & 7) << 3;
            const unsigned short* gp = w2t + (size_t)(t * NB + c) * HID + kc * 64 + kl;
            unsigned short* lp = &u.g.w2[buf][ob];
            __builtin_amdgcn_global_load_lds(
                (const __attribute__((address_space(1))) unsigned int*)gp,
                (__attribute__((address_space(3))) unsigned int*)lp, 16, 0, 0);
        }
    };

    float jf[2][4] = {{1.f,1.f,1.f,1.f},{1.f,1.f,1.f,1.f}};

    stage(0);
    #pragma unroll 1
    for (int t = 0; t < 8; ++t) {
        f32x4 acc[2][4];
        #pragma unroll
        for (int rt = 0; rt < 2; ++rt)
            #pragma unroll
            for (int ct = 0; ct < 4; ++ct) acc[rt][ct] = (f32x4){0.f, 0.f, 0.f, 0.f};

        #pragma unroll
        for (int kc = 0; kc < 4; ++kc) {          // STATIC unroll -> static afr idx
            __syncthreads();                       // chunk staged; prev buf readers done
            const int n = t * 4 + kc;
            if (n < 31) stage(n + 1);
            const unsigned short* wsb = u.g.w2[kc & 1];
            #pragma unroll
            for (int ks = 0; ks < 2; ++ks) {
                const int kf = kc * 2 + ks;        // compile-time
                const int klog = ks * 32 + quad * 8;
                #pragma unroll
                for (int ct = 0; ct < 4; ++ct) {
                    const int c = cw * 64 + ct * 16 + l15;
                    const bf16x8 bf = *(const bf16x8*)&wsb[c * 64 + (klog ^ ksw)];
                    acc[0][ct] = __builtin_amdgcn_mfma_f32_16x16x32_bf16(afr[0][kf], bf, acc[0][ct], 0, 0, 0);
                    acc[1][ct] = __builtin_amdgcn_mfma_f32_16x16x32_bf16(afr[1][kf], bf, acc[1][ct], 0, 0, 0);
                }
            }
        }

        // ---- fold b2 (L2-hot global) into the accumulator path
        float bb[4];
        #pragma unroll
        for (int ct = 0; ct < 4; ++ct)
            bb[ct] = b2[t * NB + cw * 64 + ct * 16 + l15] * LOG2E;

        // ---- local epilogue: 64-col half-row quantities, then triple exchange
        #pragma unroll
        for (int rt = 0; rt < 2; ++rt)
            #pragma unroll
            for (int i = 0; i < 4; ++i) {
                const int row = rw * 32 + rt * 16 + quad * 4 + i;
                const float alpha = xs[row * XC + 8 + t] * 128.f;   // broadcast
                const float fb = floorf(alpha);
                const int bin = min(max((int)fb, 0), 127);
                float e[4];
                #pragma unroll
                for (int ct = 0; ct < 4; ++ct) e[ct] = EXP2F(acc[rt][ct][i] + bb[ct]);
                const float P1 = e[0], P2 = P1 + e[1], P3 = P2 + e[2], P4 = P3 + e[3];
                const int bl = bin - cw * 64;              // local bin (may be <0 or >=64)
                int thr = (bl - l15 + 15) >> 4;            // count of local cols < bl
                thr = min(max(thr, 0), 4);                 // clamps make merge additive
                const float sA = (thr & 1) ? P1 : 0.f;
                const float sB = (thr & 1) ? P3 : P2;
                float num = (thr & 2) ? sB : sA;
                num = (thr >= 4) ? P4 : num;
                const int cbl = bl >> 4;
                const float t1 = (cbl & 1) ? e[1] : e[0];
                const float t2 = (cbl & 1) ? e[3] : e[2];
                const float es = (cbl & 2) ? t2 : t1;
                float eb = (((unsigned)bl < 64u) && ((bin & 15) == l15)) ? es : 0.f;
                float tot = P4;
                tot = red16(tot); num = red16(num); eb = red16(eb);
                if (l15 == 0) {
                    const f32x4 tr = {tot, num, eb, 0.f};
                    *(f32x4*)&u.g.mrg[cw][row][0] = tr;
                }
            }
        __syncthreads();                                   // publish triples

        // ---- cross-wave combine (additive), done by the cw=0 waves
        if (cw == 0) {
            #pragma unroll
            for (int rt = 0; rt < 2; ++rt)
                #pragma unroll
                for (int i = 0; i < 4; ++i) {
                    const int row = rw * 32 + rt * 16 + quad * 4 + i;
                    if (l15 == 0) {
                        const f32x4 pa = *(const f32x4*)&u.g.mrg[0][row][0];
                        const f32x4 pb = *(const f32x4*)&u.g.mrg[1][row][0];
                        const float T   = pa[0] + pb[0];
                        const float nm  = pa[1] + pb[1];
                        const float ebv = pa[2] + pb[2];
                        const float alpha = xs[row * XC + 8 + t] * 128.f;
                        const float fr = alpha - floorf(alpha);
                        const float inv = RCPF(T);
                        jf[rt][i] *= 128.f * ebv * inv;
                        xs[row * XC + 8 + t] = fmaf(ebv, fr, nm) * inv;
                    }
                }
        }
        // next t's first __syncthreads protects mrg reuse and xs ordering
    }

    // jacobian into xs, then one fully-coalesced block copy-out
    if (cw == 0 && l15 == 0) {
        #pragma unroll
        for (int rt = 0; rt < 2; ++rt)
            #pragma unroll
            for (int i = 0; i < 4; ++i) {
                const int row = rw * 32 + rt * 16 + quad * 4 + i;
                xs[row * XC + 16] *= jf[rt][i];
            }
    }
    __syncthreads();
    for (int i = tid; i < ROWSB * XC; i += 256) out[r0 * XC + i] = xs[i];
}

extern "C" void kernel_launch(void* const* d_in, const int* in_sizes, int n_in,
                              void* d_out, int out_size, void* d_ws, size_t ws_size,
                              hipStream_t stream) {
    (void)in_sizes; (void)n_in; (void)ws_size; (void)out_size;
    prep_w2<<<128, 256, 0, stream>>>((const float*)d_in[3], (unsigned short*)d_ws);
    gplc6<<<NROWS / ROWSB, 256, 0, stream>>>(
        (const float*)d_in[0], (const float*)d_in[1], (const float*)d_in[2],
        (const unsigned short*)d_ws, (const float*)d_in[4], (float*)d_out);
}

// Round 7
// 183.165 us; speedup vs baseline: 1.1234x; 1.1234x over previous
//
#include <hip/hip_runtime.h>
#include <math.h>

#define NROWS 131072
#define XC    17      // FLOW_SIZE+1
#define ROWSB 64      // rows per block
#define HID   256
#define NB    128
#define NCOL  1024
#define LOG2E 1.44269504088896340736f

typedef __attribute__((ext_vector_type(8))) short bf16x8;
typedef __attribute__((ext_vector_type(4))) float f32x4;

#if __has_builtin(__builtin_amdgcn_exp2f)
#define EXP2F(v) __builtin_amdgcn_exp2f(v)
#else
#define EXP2F(v) exp2f(v)
#endif
#if __has_builtin(__builtin_amdgcn_rcpf)
#define RCPF(v) __builtin_amdgcn_rcpf(v)
#else
#define RCPF(v) (1.f / (v))
#endif

__device__ __forceinline__ unsigned short f2bf(float f) {
    unsigned int u = __float_as_uint(f);
    return (unsigned short)((u + 0x7FFFu + ((u >> 16) & 1u)) >> 16);  // RNE
}

// 16-lane reduction on the VALU via DPP (validated; no LDS-pipe traffic).
__device__ __forceinline__ float red16(float v) {
    int x;
    x = __builtin_amdgcn_update_dpp(0, __float_as_int(v), 0xB1, 0xF, 0xF, true);
    v += __int_as_float(x);
    x = __builtin_amdgcn_update_dpp(0, __float_as_int(v), 0x4E, 0xF, 0xF, true);
    v += __int_as_float(x);
    x = __builtin_amdgcn_update_dpp(0, __float_as_int(v), 0x141, 0xF, 0xF, true);
    v += __int_as_float(x);
    x = __builtin_amdgcn_update_dpp(0, __float_as_int(v), 0x140, 0xF, 0xF, true);
    v += __int_as_float(x);
    return v;
}

// R13: coalesced LDS-transpose prep (unchanged).
__global__ void prep_w2(const float* __restrict__ W2, unsigned short* __restrict__ w2t) {
    __shared__ __align__(16) unsigned short tkT[32][80];  // [col][k], stride 160B
    const int tid = threadIdx.x;
    const int k0 = (blockIdx.x & 3) * 64;
    const int c0 = (blockIdx.x >> 2) * 32;
    const int c4 = (tid & 7) * 4;        // 4-col group
    const int kk = (tid >> 3) * 2;       // k-pair
    const float4 r0 = *(const float4*)&W2[(size_t)(k0 + kk) * NCOL + c0 + c4];
    const float4 r1 = *(const float4*)&W2[(size_t)(k0 + kk + 1) * NCOL + c0 + c4];
    const float v0[4] = {r0.x, r0.y, r0.z, r0.w};
    const float v1[4] = {r1.x, r1.y, r1.z, r1.w};
    #pragma unroll
    for (int i = 0; i < 4; ++i) {
        const unsigned int p = (unsigned int)f2bf(v0[i] * LOG2E)
                             | ((unsigned int)f2bf(v1[i] * LOG2E) << 16);
        *(unsigned int*)&tkT[c4 + i][kk] = p;
    }
    __syncthreads();
    const int g = tid & 7, c = tid >> 3;
    const uint4 q = *(const uint4*)&tkT[c][g * 8];
    *(uint4*)&w2t[(size_t)(c0 + c) * HID + k0 + ((g ^ (c & 7)) << 3)] = q;
}

// R20: R18's validated 4-deep staging + counted vmcnt, PLUS the missing
// piece (m196: the interleave IS the lever): B-fragments register-double-
// buffered. Phase n prefetches phase n+1's 8 ds_read_b128 into pNXT while
// the MFMA cluster consumes pCUR with ZERO same-phase LDS dependency.
// Buffer index (t*8+n)&3 == n&3: compile-time. pA/pB alternation static.
// vmcnt: publish m+1 at barrier(m): steady-state vmcnt(2), tail 0.
__global__ __launch_bounds__(256, 3)
void gplc6(const float* __restrict__ x,
           const float* __restrict__ W1,
           const float* __restrict__ b1,
           const unsigned short* __restrict__ w2t,
           const float* __restrict__ b2,
           float* __restrict__ out)
{
    __shared__ float xs[ROWSB * XC];                       // 4352 B
    __shared__ __align__(16) union {
        unsigned short hb[32 * HID];                       // 16 KB (phase-1 chunk)
        struct {
            unsigned short w2[4][64 * 64];                 // 32 KB (4-deep staging)
            unsigned short b2s[NCOL];                      // 2 KB  (bf16 b2*LOG2E)
        } g;
    } u;                                                   // 34816 B; total 39168 B

    const int tid  = threadIdx.x;
    const int lane = tid & 63;
    const int w    = tid >> 6;        // wave 0..3 -> rows w*16..w*16+15
    const int quad = lane >> 4;
    const int l15  = lane & 15;
    const int wr   = w * 16;
    const int ksw  = (lane & 7) << 3; // B-frag k swizzle (validated: 0 conflicts)
    const size_t r0 = (size_t)blockIdx.x * ROWSB;

    for (int i = tid; i < ROWSB * XC; i += 256) xs[i] = x[r0 * XC + i];
    const int cp = tid & 127, hlf = tid >> 7;
    float w1r[16];
    #pragma unroll
    for (int i = 0; i < 8; ++i) {
        const float2 t2 = *(const float2*)&W1[i * HID + 2 * cp];
        w1r[2 * i] = t2.x; w1r[2 * i + 1] = t2.y;
    }
    const float2 b1v = *(const float2*)&b1[2 * cp];
    __syncthreads();

    // ---- phase 1 (2 chunks of 32 rows): h = relu(xA@W1+b1) -> bf16 LDS,
    // granule-XOR row swizzle; per-chunk A-fragment loads by owning waves.
    bf16x8 afr[8];
    #pragma unroll
    for (int ch = 0; ch < 2; ++ch) {
        for (int r = 0; r < 16; ++r) {
            const int lrow = hlf * 16 + r;          // 0..31 within chunk
            const int row  = ch * 32 + lrow;
            float a0 = b1v.x, a1 = b1v.y;
            #pragma unroll
            for (int i = 0; i < 8; ++i) {
                const float xv = xs[row * XC + i];
                a0 = fmaf(xv, w1r[2 * i], a0);
                a1 = fmaf(xv, w1r[2 * i + 1], a1);
            }
            a0 = fmaxf(a0, 0.f); a1 = fmaxf(a1, 0.f);
            const int eidx = lrow * HID + (((cp >> 2) ^ (row & 15)) << 3) + ((cp & 3) << 1);
            *(unsigned int*)&u.hb[eidx] = (unsigned int)f2bf(a0) | ((unsigned int)f2bf(a1) << 16);
        }
        __syncthreads();
        if ((w >> 1) == ch) {
            #pragma unroll
            for (int kf = 0; kf < 8; ++kf) {
                const int row = wr + l15;              // row&15 == l15
                afr[kf] = *(const bf16x8*)&u.hb[(row & 31) * HID + (((kf * 4 + quad) ^ l15) << 3)];
            }
        }
        __syncthreads();           // chunk buffer dead; safe to overwrite
    }
    // union region becomes 4-deep w2 staging + b2s

    // b2 -> LDS bf16 once (keeps the t-loop free of vmcnt-counted globals).
    for (int i = tid; i < NCOL; i += 256) u.g.b2s[i] = f2bf(b2[i] * LOG2E);
    asm volatile("s_waitcnt lgkmcnt(0)" ::: "memory");
    __builtin_amdgcn_sched_barrier(0);

    // stage chunk m (m = t*8 + cj*4 + kc): 64 cols x 64 k = 8 KB, buf = m&3.
    auto stage = [&](int m) {
        const int t = m >> 3, cj = (m >> 2) & 1, buf = m & 3;
        #pragma unroll
        for (int j = 0; j < 2; ++j) {
            const int ci  = (w * 2 + j) * 8 + (lane >> 3);     // local col 0..63
            const int col = t * NB + cj * 64 + ci;
            const int kl  = (lane & 7) << 3;
            const unsigned short* gp = w2t + (size_t)col * HID + buf * 64 + kl;
            unsigned short* lp = &u.g.w2[buf][(w * 2 + j) * 512]; // wave-uniform base
            __builtin_amdgcn_global_load_lds(
                (const __attribute__((address_space(1))) unsigned int*)gp,
                (__attribute__((address_space(3))) unsigned int*)lp, 16, 0, 0);
        }
    };

    // register prefetch of one phase's 8 B-frags from staged LDS buffer `bi`
    auto prefetch = [&](bf16x8* dst, int bi) {
        const unsigned short* wsb = u.g.w2[bi];
        #pragma unroll
        for (int ks = 0; ks < 2; ++ks) {
            const int klog = ks * 32 + quad * 8;
            #pragma unroll
            for (int ci = 0; ci < 4; ++ci) {
                const int c = ci * 16 + l15;
                dst[ks * 4 + ci] = *(const bf16x8*)&wsb[c * 64 + (klog ^ ksw)];
            }
        }
    };

    float jf[4] = {1.f, 1.f, 1.f, 1.f};
    bf16x8 pA[8], pB[8];
    f32x4 acc[8];

// one sub-phase: stage m+3, prefetch phase m+1 into NXT, MFMA phase m from CUR
#define SUBPHASE(N, CUR, NXT)                                                   \
    {                                                                           \
        const int m_ = t * 8 + (N);                                             \
        if (m_ <= 60) stage(m_ + 3);                                            \
        if (m_ < 63) prefetch(NXT, ((N) + 1) & 3);                              \
        __builtin_amdgcn_s_setprio(1);                                          \
        _Pragma("unroll")                                                       \
        for (int ks = 0; ks < 2; ++ks) {                                        \
            _Pragma("unroll")                                                   \
            for (int ci = 0; ci < 4; ++ci) {                                    \
                acc[(((N) >> 2) & 1) * 4 + ci] =                                \
                    __builtin_amdgcn_mfma_f32_16x16x32_bf16(                    \
                        afr[((N) & 3) * 2 + ks], CUR[ks * 4 + ci],              \
                        acc[(((N) >> 2) & 1) * 4 + ci], 0, 0, 0);               \
            }                                                                   \
        }                                                                       \
        __builtin_amdgcn_s_setprio(0);                                          \
    }

// wait+barrier closing sub-phase N: publish chunk m+2 (vmcnt(2) steady, 0 tail)
#define WB(N)                                                                   \
    {                                                                           \
        if (t < 7 || (N) <= 4) { asm volatile("s_waitcnt vmcnt(2)" ::: "memory"); } \
        else                   { asm volatile("s_waitcnt vmcnt(0)" ::: "memory"); } \
        __builtin_amdgcn_s_barrier();                                           \
    }

    // prologue: 3 chunks in flight; publish 0 and 1; preload phase-0 frags
    stage(0); stage(1); stage(2);
    asm volatile("s_waitcnt vmcnt(2)" ::: "memory");
    __builtin_amdgcn_s_barrier();
    prefetch(pA, 0);

    #pragma unroll 1
    for (int t = 0; t < 8; ++t) {
        #pragma unroll
        for (int ct = 0; ct < 8; ++ct) acc[ct] = (f32x4){0.f, 0.f, 0.f, 0.f};

        SUBPHASE(0, pA, pB) WB(0)
        SUBPHASE(1, pB, pA) WB(1)
        SUBPHASE(2, pA, pB) WB(2)
        SUBPHASE(3, pB, pA) WB(3)
        SUBPHASE(4, pA, pB) WB(4)
        SUBPHASE(5, pB, pA) WB(5)
        SUBPHASE(6, pA, pB) WB(6)
        SUBPHASE(7, pB, pA)

        // ---- fused epilogue for transform t (wave covers full 128-col row)
        float bb[8];
        #pragma unroll
        for (int ct = 0; ct < 8; ++ct)
            bb[ct] = __uint_as_float((unsigned int)u.g.b2s[t * NB + ct * 16 + l15] << 16);
        #pragma unroll
        for (int i = 0; i < 4; ++i) {
            const int row = wr + quad * 4 + i;
            const float alpha = xs[row * XC + 8 + t] * 128.f;   // broadcast
            const float fb = floorf(alpha);
            const int bin = min(max((int)fb, 0), 127);
            const float fr = alpha - fb;
            float e[8];
            #pragma unroll
            for (int ct = 0; ct < 8; ++ct) e[ct] = EXP2F(acc[ct][i] + bb[ct]);
            const float P1 = e[0],      P2 = P1 + e[1], P3 = P2 + e[2], P4 = P3 + e[3];
            const float P5 = P4 + e[4], P6 = P5 + e[5], P7 = P6 + e[6], P8 = P7 + e[7];
            int thr = (bin - l15 + 15) >> 4;           // ceil((bin-l15)/16)
            thr = min(max(thr, 0), 8);
            const float sA = (thr & 1) ? P1 : 0.f;
            const float sB = (thr & 1) ? P3 : P2;
            const float sC = (thr & 1) ? P5 : P4;
            const float sD = (thr & 1) ? P7 : P6;
            const float sE = (thr & 2) ? sB : sA;
            const float sF = (thr & 2) ? sD : sC;
            float num = (thr & 4) ? sF : sE;
            num = (thr >= 8) ? P8 : num;
            const int cb = bin >> 4;
            const float t1 = (cb & 1) ? e[1] : e[0];
            const float t2 = (cb & 1) ? e[3] : e[2];
            const float t3 = (cb & 1) ? e[5] : e[4];
            const float t4 = (cb & 1) ? e[7] : e[6];
            const float u1 = (cb & 2) ? t2 : t1;
            const float u2 = (cb & 2) ? t4 : t3;
            const float es = (cb & 4) ? u2 : u1;
            float eb  = ((bin & 15) == l15) ? es : 0.f;
            float tot = P8;
            tot = red16(tot); num = red16(num); eb = red16(eb);
            const float inv = RCPF(tot);
            jf[i] *= 128.f * eb * inv;
            if (l15 == 0) xs[row * XC + 8 + t] = fmaf(eb, fr, num) * inv;
        }
        if (t < 7) WB(7)
    }
#undef SUBPHASE
#undef WB

    // jacobian into xs, then one fully-coalesced block copy-out
    if (l15 == 0) {
        #pragma unroll
        for (int i = 0; i < 4; ++i) {
            const int row = wr + quad * 4 + i;
            xs[row * XC + 16] *= jf[i];
        }
    }
    __syncthreads();
    for (int i = tid; i < ROWSB * XC; i += 256) out[r0 * XC + i] = xs[i];
}

extern "C" void kernel_launch(void* const* d_in, const int* in_sizes, int n_in,
                              void* d_out, int out_size, void* d_ws, size_t ws_size,
                              hipStream_t stream) {
    (void)in_sizes; (void)n_in; (void)ws_size; (void)out_size;
    prep_w2<<<128, 256, 0, stream>>>((const float*)d_in[3], (unsigned short*)d_ws);
    gplc6<<<NROWS / ROWSB, 256, 0, stream>>>(
        (const float*)d_in[0], (const float*)d_in[1], (const float*)d_in[2],
        (const unsigned short*)d_ws, (const float*)d_in[4], (float*)d_out);
}